// Round 3
// baseline (194.661 us; speedup 1.0000x reference)
//
#include <hip/hip_runtime.h>
#include <math.h>

#define NN 32768
#define BB 16
#define LL 2048
#define NE (NN*9)
#define EPSF 1e-6f
#define CAP 32

// ---- output layout (flat float32, reference tuple order) ----
#define O_NODEPOS 0
#define O_DISNODE (NN*16)
#define O_ANGNODE (O_DISNODE + NN*48)
#define O_DIRNODE (O_ANGNODE + NN*12)
#define O_EIDX    (O_DIRNODE + NN*9)
#define O_CTX     (O_EIDX + 2*NE)
#define O_INTER   (O_CTX + NE)
#define O_EDGEPOS (O_INTER + NE)
#define O_DISEDGE (O_EDGEPOS + NE*16)
#define O_ANGEDGE (O_DISEDGE + NE*64)
#define O_DIREDGE (O_ANGEDGE + NE*4)

struct F3 { float x, y, z; };
__device__ __forceinline__ F3 mkf3(float x, float y, float z){ F3 r; r.x=x; r.y=y; r.z=z; return r; }
__device__ __forceinline__ F3 subf3(F3 a, F3 b){ return mkf3(a.x-b.x, a.y-b.y, a.z-b.z); }
__device__ __forceinline__ float dotf3(F3 a, F3 b){ return a.x*b.x + a.y*b.y + a.z*b.z; }
__device__ __forceinline__ F3 crossf3(F3 a, F3 b){
  return mkf3(a.y*b.z - a.z*b.y, a.z*b.x - a.x*b.z, a.x*b.y - a.y*b.x);
}
__device__ __forceinline__ F3 normf3(F3 v){
  float n = sqrtf(v.x*v.x + v.y*v.y + v.z*v.z);
  float m = fmaxf(n, 1e-12f);
  return mkf3(v.x/m, v.y/m, v.z/m);
}
__device__ __forceinline__ float sgnf(float x){ return (x > 0.f) ? 1.f : ((x < 0.f) ? -1.f : 0.f); }
__device__ __forceinline__ float clampf(float x, float lo, float hi){ return fminf(fmaxf(x, lo), hi); }

__device__ __forceinline__ F3 ldatom(const float* __restrict__ X, int n, int a){
  const float* p = X + (size_t)n*12 + a*3;
  return mkf3(p[0], p[1], p[2]);
}
__device__ __forceinline__ float dist_eps(F3 a, F3 b){
  F3 d = subf3(a, b);
  return sqrtf(dotf3(d, d) + EPSF);
}
// freq[t] = 10000^(-t/8), t=0..7
__device__ __forceinline__ float frq(int t){
  const float F[8] = {1.0f, 0.31622776601683794f, 0.1f, 0.031622776601683794f,
                      0.01f, 0.0031622776601683794f, 0.001f, 0.00031622776601683794f};
  return F[t];
}
__device__ __forceinline__ void rbf16(float* __restrict__ dst, float d){
  #pragma unroll
  for (int t = 0; t < 16; ++t){
    float mu = (float)t * (20.0f/15.0f);
    float z = (d - mu) * (1.0f/1.25f);
    dst[t] = __expf(-z*z);
  }
}

// CA coord of batch-local node il from the skewed LDS stage
__device__ __forceinline__ F3 ca_lds(const float4* __restrict__ sca, int il){
  const float4 v = sca[il + (il >> 8)];
  return mkf3(v.x, v.y, v.z);
}

// O frame for node n, CA coords read from the block's LDS stage.
// Valid because every node with a non-zero frame (per the boundary mask)
// references only CA coords within its own 2048-node batch.
__device__ __forceinline__ void computeO_sca(const float4* __restrict__ sca, int n,
                                             F3& O0, F3& O1, F3& O2){
  const int l = n & (LL-1);
  const int b = n >> 11;
  const bool fm = !((l <= 1) || ((l >= LL-2) && (b < BB-1)));
  const bool has = fm && (n >= 1) && (n <= NN-3);
  if (has){
    F3 cm = ca_lds(sca, l-1), c0 = ca_lds(sca, l), cp = ca_lds(sca, l+1);
    F3 uc2 = normf3(subf3(c0, cm));
    F3 uc1 = normf3(subf3(cp, c0));
    F3 nf  = normf3(crossf3(uc2, uc1));
    F3 o1  = normf3(subf3(uc2, uc1));
    O0 = o1; O1 = nf; O2 = crossf3(o1, nf);
  } else {
    O0 = mkf3(0,0,0); O1 = mkf3(0,0,0); O2 = mkf3(0,0,0);
  }
}

// ---------------- node-feature body ----------------
__device__ void node_body(const float* __restrict__ X,
                          const float4* __restrict__ sca,
                          float* __restrict__ out,
                          int n){
  const int l = n & (LL-1);
  const int b = n >> 11;

  F3 O0, O1, O2;
  computeO_sca(sca, n, O0, O1, O2);

  // ---- node_pos ----
  {
    const float p = (float)l;
    #pragma unroll
    for (int t = 0; t < 8; ++t){
      float sv, cv;
      __sincosf(p * frq(t), &sv, &cv);
      out[O_NODEPOS + n*16 + t] = cv;
      out[O_NODEPOS + n*16 + 8 + t] = sv;
    }
  }

  // ---- dis_node ----
  const F3 x0 = ldatom(X,n,0), x1 = ldatom(X,n,1), x2 = ldatom(X,n,2), x3 = ldatom(X,n,3);
  {
    float buf[16];
    rbf16(buf, dist_eps(x0, x1));
    #pragma unroll
    for (int t=0;t<16;++t) out[O_DISNODE + n*48 + t] = buf[t];
    rbf16(buf, dist_eps(x2, x1));
    #pragma unroll
    for (int t=0;t<16;++t) out[O_DISNODE + n*48 + 16 + t] = buf[t];
    rbf16(buf, dist_eps(x3, x1));
    #pragma unroll
    for (int t=0;t<16;++t) out[O_DISNODE + n*48 + 32 + t] = buf[t];
  }

  // ---- angle_node ----
  {
    const bool am = !((l <= 1) || ((l == LL-1) && (b < BB-1)));
    const float amf = am ? 1.f : 0.f;
    const int t0 = 3*n - 1;
    F3 P[6];
    #pragma unroll
    for (int q = 0; q < 6; ++q){
      int t = t0 + q;
      t = t < 0 ? 0 : (t > 3*NN - 1 ? 3*NN - 1 : t);
      const int nn2 = t / 3, aa = t - nn2*3;
      P[q] = ldatom(X, nn2, aa);
    }
    F3 U[5];
    #pragma unroll
    for (int q = 0; q < 5; ++q) U[q] = normf3(subf3(P[q+1], P[q]));
    #pragma unroll
    for (int cc = 0; cc < 3; ++cc){
      const int m = 3*n + cc - 1;
      float cD = 1.f, sD = 0.f, cA = 1.f, sA = 0.f;
      if (m >= 0 && m <= 3*NN - 4){
        const F3 u2 = U[cc], u1 = U[cc+1], u0 = U[cc+2];
        const F3 n2 = normf3(crossf3(u2, u1));
        const F3 n1 = normf3(crossf3(u1, u0));
        const float cd_ = clampf(dotf3(n2, n1), -1.f + EPSF, 1.f - EPSF);
        const float sg = sgnf(dotf3(u2, n1));
        cD = cd_;
        sD = sg * sqrtf(fmaxf(1.f - cd_*cd_, 0.f));
        const float ca_ = clampf(dotf3(u2, u1), -1.f + EPSF, 1.f - EPSF);
        cA = ca_;
        sA = sqrtf(fmaxf(1.f - ca_*ca_, 0.f));
      }
      out[O_ANGNODE + n*12 + cc]     = cD * amf;
      out[O_ANGNODE + n*12 + 3 + cc] = sD * amf;
      out[O_ANGNODE + n*12 + 6 + cc] = cA * amf;
      out[O_ANGNODE + n*12 + 9 + cc] = sA * amf;
    }
  }

  // ---- direct_node ----
  {
    const F3 vs[3] = { subf3(x0, x1), subf3(x2, x1), subf3(x3, x1) };
    #pragma unroll
    for (int ai = 0; ai < 3; ++ai){
      F3 w = mkf3(dotf3(O0, vs[ai]), dotf3(O1, vs[ai]), dotf3(O2, vs[ai]));
      w = normf3(w);
      out[O_DIRNODE + n*9 + ai*3 + 0] = w.x;
      out[O_DIRNODE + n*9 + ai*3 + 1] = w.y;
      out[O_DIRNODE + n*9 + ai*3 + 2] = w.z;
    }
  }
}

// =================== single fused kernel: 64 rows per block ===================
// Per block: stage batch CA -> top-9 (2-pass, reg-blocked 4 rows/thread) ->
// node features + ALL edge features for its own 64 rows. No cross-block deps:
// edge endpoints are always in the staged batch, and frames are recomputed
// on the fly from LDS (bit-identical FP sequence to the node path).
__global__ __launch_bounds__(256, 2) void fused_kernel(const float* __restrict__ X,
                                                       const int* __restrict__ seg,
                                                       float* __restrict__ out){
  __shared__ float4 sca[LL + (LL >> 8)];           // 32.9 KB skewed CA stage
  __shared__ union {                               // 20.7 KB, time-disjoint uses
    unsigned long long eb[64][CAP];                //   topk rescan buffer
    float dir[5184];                               //   direct_edge staging
  } u;
  __shared__ int ecnt[64];
  __shared__ int ecol[576];                        // this block's 9 cols per row

  const int tid = threadIdx.x;
  const int block0 = blockIdx.x * 64;              // 64 rows per block
  const int base = (block0 >> 11) << 11;

  if (tid < 64) ecnt[tid] = 0;
  for (int p = tid; p < LL; p += 256){
    const float* xp = X + (size_t)(base + p)*12 + 3;   // CA atom
    sca[p + (p >> 8)] = make_float4(xp[0], xp[1], xp[2], 0.f);
  }
  __syncthreads();

  // ---------------- top-9 ----------------
  const int rg = tid >> 4;         // row group 0..15 (4 rows each)
  const int kq = tid & 15;         // lane within group: 128-candidate chunk
  const int r0 = rg << 2;
  float4 ci[4];
  #pragma unroll
  for (int q = 0; q < 4; ++q){
    const int il = (block0 - base) + r0 + q;
    ci[q] = sca[il + (il >> 8)];
  }
  const float4* __restrict__ basep = &sca[(kq << 7) + (kq >> 1)];

  float v0[4], v1[4], v2[4];
  #pragma unroll
  for (int q = 0; q < 4; ++q){
    v0[q] = __builtin_inff(); v1[q] = __builtin_inff(); v2[q] = __builtin_inff();
  }

  #pragma unroll 8
  for (int jj = 0; jj < 128; ++jj){
    const float4 cj = basep[jj];
    #pragma unroll
    for (int q = 0; q < 4; ++q){
      const float dx = ci[q].x - cj.x, dy = ci[q].y - cj.y, dz = ci[q].z - cj.z;
      const float key = fmaf(dz, dz, fmaf(dy, dy, dx*dx));
      // 4-op sorted-top3 insertion (same kept set as min/max cascade)
      const float nv0 = fminf(key, v0[q]);
      const float nv1 = __builtin_amdgcn_fmed3f(key, v0[q], v1[q]);
      const float nv2 = fminf(v2[q], fmaxf(key, v1[q]));
      v0[q] = nv0; v1[q] = nv1; v2[q] = nv2;
    }
  }

  // 9 pop-rounds over the 16 sorted 3-lists -> t9 >= true 9th smallest
  float t9[4];
  #pragma unroll
  for (int q = 0; q < 4; ++q){
    float a0 = v0[q], a1 = v1[q], a2 = v2[q];
    float t = 0.f;
    #pragma unroll
    for (int it = 0; it < 9; ++it){
      float m = a0;
      m = fminf(m, __shfl_xor(m, 1, 16));
      m = fminf(m, __shfl_xor(m, 2, 16));
      m = fminf(m, __shfl_xor(m, 4, 16));
      m = fminf(m, __shfl_xor(m, 8, 16));
      const bool pop = (a0 == m);
      a0 = pop ? a1 : a0;
      a1 = pop ? a2 : a1;
      a2 = pop ? __builtin_inff() : a2;
      t = m;
    }
    t9[q] = t;
  }

  // rescan: exact (s,idx) for everything at or below the threshold
  #pragma unroll 4
  for (int jj = 0; jj < 128; ++jj){
    const float4 cj = basep[jj];
    #pragma unroll
    for (int q = 0; q < 4; ++q){
      const float dx = ci[q].x - cj.x, dy = ci[q].y - cj.y, dz = ci[q].z - cj.z;
      const float s = fmaf(dz, dz, fmaf(dy, dy, dx*dx));   // bit-identical to pass 1
      if (s <= t9[q]){
        const int slot = atomicAdd(&ecnt[r0 + q], 1);
        if (slot < CAP)
          u.eb[r0 + q][slot] = ((unsigned long long)__float_as_uint(s) << 32)
                             | (unsigned)((kq << 7) + jj);
      }
    }
  }
  __syncthreads();

  if (kq < 4){
    const int r = r0 + kq;
    const int m = min(ecnt[r], CAP);
    unsigned long long kk[9];
    #pragma unroll
    for (int t = 0; t < 9; ++t) kk[t] = ~0ull;
    for (int j = 0; j < m; ++j){
      unsigned long long key = u.eb[r][j];
      #pragma unroll
      for (int t = 0; t < 9; ++t){
        const bool lt = key < kk[t];
        const unsigned long long mn = lt ? key : kk[t];
        const unsigned long long mx = lt ? kk[t] : key;
        kk[t] = mn; key = mx;
      }
    }
    const int n = block0 + r;
    const int be = n * 9;
    #pragma unroll
    for (int t = 0; t < 9; ++t){
      const int cidx = base + (int)(unsigned)kk[t];
      out[O_EIDX + be + t] = (float)n;
      out[O_EIDX + NE + be + t] = (float)cidx;
      ecol[r*9 + t] = cidx;
    }
  }
  __syncthreads();   // ecol ready; u.eb dead -> u.dir reusable

  // ---------------- node features (wave 0, 1 node/thread) ----------------
  if (tid < 64) node_body(X, sca, out, block0 + tid);

  // ---------------- small edge features ----------------
  for (int idx = tid; idx < 576; idx += 256){
    const int r = (int)((unsigned)idx / 9u);
    const int n = block0 + r;
    const int c = ecol[idx];
    const int e = block0*9 + idx;

    const float ctx = (seg[n] == seg[c]) ? 1.f : 0.f;
    out[O_CTX + e]   = ctx;
    out[O_INTER + e] = 1.f - ctx;

    // edge_pos
    {
      const float p = (float)(n - c);
      float cv[8], sv[8];
      #pragma unroll
      for (int t = 0; t < 8; ++t) __sincosf(p * frq(t), &sv[t], &cv[t]);
      float4* dst = reinterpret_cast<float4*>(out + O_EDGEPOS + (size_t)e*16);
      dst[0] = make_float4(cv[0],cv[1],cv[2],cv[3]);
      dst[1] = make_float4(cv[4],cv[5],cv[6],cv[7]);
      dst[2] = make_float4(sv[0],sv[1],sv[2],sv[3]);
      dst[3] = make_float4(sv[4],sv[5],sv[6],sv[7]);
    }

    F3 Ar0, Ar1, Ar2, Ac0, Ac1, Ac2;
    computeO_sca(sca, n, Ar0, Ar1, Ar2);
    computeO_sca(sca, c, Ac0, Ac1, Ac2);

    // angle_edge: quaternion of R = Or^T * Oc
    {
      const float R00 = Ar0.x*Ac0.x + Ar1.x*Ac1.x + Ar2.x*Ac2.x;
      const float R01 = Ar0.x*Ac0.y + Ar1.x*Ac1.y + Ar2.x*Ac2.y;
      const float R02 = Ar0.x*Ac0.z + Ar1.x*Ac1.z + Ar2.x*Ac2.z;
      const float R10 = Ar0.y*Ac0.x + Ar1.y*Ac1.x + Ar2.y*Ac2.x;
      const float R11 = Ar0.y*Ac0.y + Ar1.y*Ac1.y + Ar2.y*Ac2.y;
      const float R12 = Ar0.y*Ac0.z + Ar1.y*Ac1.z + Ar2.y*Ac2.z;
      const float R20 = Ar0.z*Ac0.x + Ar1.z*Ac1.x + Ar2.z*Ac2.x;
      const float R21 = Ar0.z*Ac0.y + Ar1.z*Ac1.y + Ar2.z*Ac2.y;
      const float R22 = Ar0.z*Ac0.z + Ar1.z*Ac1.z + Ar2.z*Ac2.z;
      const float m0 = 0.5f * sqrtf(fabsf(1.f + R00 - R11 - R22) + 1e-12f);
      const float m1 = 0.5f * sqrtf(fabsf(1.f - R00 + R11 - R22) + 1e-12f);
      const float m2 = 0.5f * sqrtf(fabsf(1.f - R00 - R11 + R22) + 1e-12f);
      const float qx = sgnf(R21 - R12) * m0;
      const float qy = sgnf(R02 - R20) * m1;
      const float qz = sgnf(R10 - R01) * m2;
      const float qw = sqrtf(fmaxf(1.f + R00 + R11 + R22, 0.f) + 1e-12f) * 0.5f;
      const float qn = fmaxf(sqrtf(qx*qx + qy*qy + qz*qz + qw*qw), 1e-12f);
      *reinterpret_cast<float4*>(out + O_ANGEDGE + (size_t)e*4) =
          make_float4(qx/qn, qy/qn, qz/qn, qw/qn);
    }

    // direct_edge -> LDS stage (flushed coalesced below)
    {
      const F3 xc1 = ca_lds(sca, c - base);
      const int atoms[3] = {0, 2, 3};
      #pragma unroll
      for (int ai = 0; ai < 3; ++ai){
        const F3 xr = ldatom(X, n, atoms[ai]);
        const F3 vv = subf3(xr, xc1);
        F3 w = mkf3(dotf3(Ac0, vv), dotf3(Ac1, vv), dotf3(Ac2, vv));
        w = normf3(w);
        u.dir[idx*9 + ai*3 + 0] = w.x;
        u.dir[idx*9 + ai*3 + 1] = w.y;
        u.dir[idx*9 + ai*3 + 2] = w.z;
      }
    }
  }
  __syncthreads();

  // coalesced flush of direct_edge (block region is contiguous: 5184 floats)
  {
    const float4* sd = reinterpret_cast<const float4*>(u.dir);
    float4* dst = reinterpret_cast<float4*>(out + O_DIREDGE + (size_t)block0*81);
    for (int w = tid; w < 1296; w += 256) dst[w] = sd[w];
  }

  // ---------------- dis_edge: (edge, atom, 4-channel group) ----------------
  for (int g = tid; g < 9216; g += 256){
    const int el = g >> 4;
    const int r = (int)((unsigned)el / 9u);
    const int n = block0 + r;
    const int c = ecol[el];
    const int a = (g >> 2) & 3;
    const int ch0 = (g & 3) << 2;
    const F3 xr = ldatom(X, n, a);
    const F3 xc = ca_lds(sca, c - base);
    const float d = dist_eps(xr, xc);
    float4 o; float z;
    z = (d - (float)(ch0+0) * (20.0f/15.0f)) * (1.0f/1.25f); o.x = __expf(-z*z);
    z = (d - (float)(ch0+1) * (20.0f/15.0f)) * (1.0f/1.25f); o.y = __expf(-z*z);
    z = (d - (float)(ch0+2) * (20.0f/15.0f)) * (1.0f/1.25f); o.z = __expf(-z*z);
    z = (d - (float)(ch0+3) * (20.0f/15.0f)) * (1.0f/1.25f); o.w = __expf(-z*z);
    reinterpret_cast<float4*>(out + O_DISEDGE)[(size_t)block0*144 + g] = o;
  }
}

extern "C" void kernel_launch(void* const* d_in, const int* in_sizes, int n_in,
                              void* d_out, int out_size, void* d_ws, size_t ws_size,
                              hipStream_t stream) {
  const float* X = (const float*)d_in[0];
  const int* seg = (const int*)d_in[1];
  float* out = (float*)d_out;
  (void)d_ws; (void)ws_size;
  fused_kernel<<<NN/64, 256, 0, stream>>>(X, seg, out);
}